// Round 5
// baseline (281.678 us; speedup 1.0000x reference)
//
#include <hip/hip_runtime.h>
#include <stdint.h>
#include <stddef.h>

#define B_ 2048
#define D_ 4096
#define E_ 512
#define N_ 8192

typedef unsigned short ushort_t;
typedef __attribute__((ext_vector_type(8))) short short8;
typedef __attribute__((ext_vector_type(4))) float floatx4;
typedef __attribute__((ext_vector_type(4))) unsigned short ushort4_t;

__device__ __forceinline__ void async_load16(const void* g, void* l) {
  __builtin_amdgcn_global_load_lds((__attribute__((address_space(1))) void*)(g),
                                   (__attribute__((address_space(3))) void*)(l), 16, 0, 0);
}

__device__ __forceinline__ ushort_t f2bf(float f) {
  unsigned int u = __float_as_uint(f);
  unsigned int r = (u + 0x7fffu + ((u >> 16) & 1u)) >> 16;
  return (ushort_t)r;
}
__device__ __forceinline__ float bf2f(ushort_t h) {
  return __uint_as_float(((unsigned int)h) << 16);
}

#define BAR() asm volatile("s_barrier" ::: "memory")
#define VMW(n) asm volatile("s_waitcnt vmcnt(" #n ")" ::: "memory")
#define LGKM0() asm volatile("s_waitcnt lgkmcnt(0)" ::: "memory")

// =====================================================================
// stats_cast: bn partial stats (blocks 0-255) || W cast (256-2303) ||
// n_wfs cast + inv-norm (2304-4351). All independent work, one launch,
// full device saturation (plain launch -- NO cooperative/grid-sync).
// =====================================================================
__global__ __launch_bounds__(256) void stats_cast(const float* __restrict__ vf,
                                                  const float* __restrict__ W,
                                                  const float* __restrict__ nw,
                                                  float* __restrict__ psum,
                                                  float* __restrict__ psq,
                                                  ushort_t* __restrict__ wb,
                                                  ushort_t* __restrict__ nwb,
                                                  float* __restrict__ inv_nw) {
  const int bid = blockIdx.x, tid = threadIdx.x;
  if (bid < 256) {
    // bn partial stats: chunk = bid>>2 (32 rows), col-quarter = bid&3
    const int chunk = bid >> 2;
    const int d4 = (bid & 3) * 256 + tid;     // float4 col in [0,1024)
    floatx4 s = {0.f, 0.f, 0.f, 0.f}, q = {0.f, 0.f, 0.f, 0.f};
    const int r0 = chunk * 32;
    for (int r = r0; r < r0 + 32; ++r) {
      floatx4 v = ((const floatx4*)(vf + (size_t)r * D_))[d4];
      s += v; q += v * v;
    }
    ((floatx4*)(psum + (size_t)chunk * D_))[d4] = s;
    ((floatx4*)(psq  + (size_t)chunk * D_))[d4] = q;
  } else if (bid < 2304) {
    // W cast: 512K float4s over 2048 blocks, 1 float4/thread
    size_t i = (size_t)(bid - 256) * 256 + tid;
    floatx4 x = ((const floatx4*)W)[i];
    ushort4_t o;
#pragma unroll
    for (int j = 0; j < 4; ++j) o[j] = f2bf(x[j]);
    ((ushort4_t*)wb)[i] = o;
  } else {
    // n_wfs cast + inv-norm: wave per row
    const int wv = tid >> 6, l = tid & 63;
    const int n = (bid - 2304) * 4 + wv;
    const floatx4* src = (const floatx4*)(nw + (size_t)n * E_);
    ushort4_t* dst = (ushort4_t*)(nwb + (size_t)n * E_);
    float s = 0.f;
#pragma unroll
    for (int k = 0; k < 2; ++k) {
      floatx4 x = src[l + 64 * k];
      ushort4_t o;
#pragma unroll
      for (int j = 0; j < 4; ++j) { o[j] = f2bf(x[j]); s += x[j] * x[j]; }
      dst[l + 64 * k] = o;
    }
    for (int off = 32; off; off >>= 1) s += __shfl_down(s, off);
    if (l == 0) inv_nw[n] = 1.f / fmaxf(sqrtf(s), 1e-8f);
  }
}

// ---------------- bn finalize (16 blocks, 1 col/thread, coalesced) + zero sumsq_e ----------------
__global__ __launch_bounds__(256) void bn_finalize(const float* __restrict__ psum,
                                                   const float* __restrict__ psq,
                                                   const float* __restrict__ gamma,
                                                   const float* __restrict__ beta,
                                                   float* __restrict__ scale,
                                                   float* __restrict__ shift,
                                                   float* __restrict__ sumsq_e) {
  const int col = blockIdx.x * 256 + threadIdx.x;   // 4096 cols over 16 blocks
  float s = 0.f, q = 0.f;
#pragma unroll 8
  for (int c = 0; c < 64; ++c) {
    s += psum[(size_t)c * D_ + col];
    q += psq[(size_t)c * D_ + col];
  }
  float mean = s * (1.0f / B_);
  float var  = q * (1.0f / B_) - mean * mean;
  float sc   = gamma[col] * rsqrtf(var + 1e-5f);
  scale[col] = sc;
  shift[col] = beta[col] - mean * sc;
  if (blockIdx.x < 8) sumsq_e[blockIdx.x * 256 + threadIdx.x] = 0.f;
}

// ---------------- fused: p_e cosine + vfn bf16 cast (one wave per row) ----------------
__global__ __launch_bounds__(256) void pe_cast(const float* __restrict__ vf,
                                               const float* __restrict__ p,
                                               const float* __restrict__ scale,
                                               const float* __restrict__ shift,
                                               ushort_t* __restrict__ vfn,
                                               float* __restrict__ pe) {
  int wv = threadIdx.x >> 6, l = threadIdx.x & 63;
  int v = blockIdx.x * 4 + wv;
  const floatx4* vf4 = (const floatx4*)(vf + (size_t)v * D_);
  const floatx4* p4  = (const floatx4*)(p  + (size_t)v * D_);
  const floatx4* sc4 = (const floatx4*)scale;
  const floatx4* sh4 = (const floatx4*)shift;
  ushort_t* vrow = vfn + (size_t)v * D_;
  float sd = 0.f, sa = 0.f, sb = 0.f;
#pragma unroll 4
  for (int k = 0; k < 16; ++k) {
    int i = l + 64 * k;
    floatx4 x = vf4[i], y = p4[i], s = sc4[i], t = sh4[i];
    ushort4_t o;
#pragma unroll
    for (int j = 0; j < 4; ++j) {
      float xn = x[j] * s[j] + t[j];
      o[j] = f2bf(xn);
      sd += xn * y[j]; sa += xn * xn; sb += y[j] * y[j];
    }
    *(ushort4_t*)(vrow + i * 4) = o;
  }
  for (int off = 32; off; off >>= 1) {
    sd += __shfl_down(sd, off); sa += __shfl_down(sa, off); sb += __shfl_down(sb, off);
  }
  if (l == 0) {
    float na = fmaxf(sqrtf(sa), 1e-8f), nb = fmaxf(sqrtf(sb), 1e-8f);
    pe[v] = sd / (na * nb);
  }
}

// =====================================================================
// GEMM1 one-pass: 64x64 tile, full K=4096 per block, grid (8,32)=256.
// Proven R2 inner loop (dbuf, T2 XOR-swizzle via pre-swizzled global
// source + swizzled ds_read, counted vmcnt(4), lgkmcnt(0)+raw barrier,
// setprio). Epilogue: bias+ReLU+bf16 store to emb + per-row sumsq via
// shfl_xor reduce + one atomicAdd per row per wave (device-scope).
// Eliminates the partial round-trip (33.6 MB) + reduce kernel + launch.
// =====================================================================
__global__ __launch_bounds__(256, 2) void gemm1_onepass(const ushort_t* __restrict__ A,
                                                        const ushort_t* __restrict__ Bt,
                                                        const float* __restrict__ bias,
                                                        ushort_t* __restrict__ emb,
                                                        float* __restrict__ sumsq_e) {
  __shared__ __align__(16) ushort_t As[2][64 * 64];
  __shared__ __align__(16) ushort_t Bs[2][64 * 64];
  floatx4 acc[2][2] = {};
  const int tid = threadIdx.x, w = tid >> 6, l = tid & 63;
  const int m16 = l & 15, q = l >> 4;
  const int wr = w >> 1, wc = w & 1;          // 2x2 waves, wave tile 32x32
  const int bm0 = blockIdx.y * 64, bn0 = blockIdx.x * 64;

  auto stageT = [&](const ushort_t* G, int r0, int t, ushort_t* buf) {
#pragma unroll
    for (int i = 0; i < 2; ++i) {
      int lin = i * 2048 + tid * 8;
      int row = lin >> 6, colp = lin & 63;
      int col = colp ^ ((row & 7) << 3);      // pre-swizzled source col
      async_load16(G + (size_t)(r0 + row) * D_ + t * 64 + col,
                   &buf[i * 2048 + w * 512]);
    }
  };

  // prologue: tiles 0 (buf0) and 1 (buf1); 8 loads issued, wait tile0 only
  stageT(A, bm0, 0, As[0]); stageT(Bt, bn0, 0, Bs[0]);
  stageT(A, bm0, 1, As[1]); stageT(Bt, bn0, 1, Bs[1]);
  VMW(4);
  BAR();

  for (int t = 0; t < 64; ++t) {
    const int cur = t & 1;
    short8 af[2][2], bf[2][2];
#pragma unroll
    for (int i = 0; i < 2; ++i) {
      int arow = wr * 32 + i * 16 + m16;
      int sw = (arow & 7) << 3;
#pragma unroll
      for (int kc = 0; kc < 2; ++kc)
        af[i][kc] = *(const short8*)&As[cur][arow * 64 + ((kc * 32 + q * 8) ^ sw)];
    }
#pragma unroll
    for (int j = 0; j < 2; ++j) {
      int brow = wc * 32 + j * 16 + m16;
      int sw = (brow & 7) << 3;
#pragma unroll
      for (int kc = 0; kc < 2; ++kc)
        bf[j][kc] = *(const short8*)&Bs[cur][brow * 64 + ((kc * 32 + q * 8) ^ sw)];
    }
    LGKM0();                 // our reads of buf[cur] complete
    BAR();                   // all waves done reading buf[cur] -> safe to overwrite
    if (t + 2 < 64) { stageT(A, bm0, t + 2, As[cur]); stageT(Bt, bn0, t + 2, Bs[cur]); }
    __builtin_amdgcn_s_setprio(1);
#pragma unroll
    for (int kc = 0; kc < 2; ++kc)
#pragma unroll
      for (int i = 0; i < 2; ++i)
#pragma unroll
        for (int j = 0; j < 2; ++j)
          acc[i][j] = __builtin_amdgcn_mfma_f32_16x16x32_bf16(af[i][kc], bf[j][kc], acc[i][j], 0, 0, 0);
    __builtin_amdgcn_s_setprio(0);
    if (t + 2 < 64) { VMW(4); } else { VMW(0); }  // buf[cur^1] landed; newest 4 in flight
    BAR();
  }

  // epilogue: bias + ReLU + bf16 cast -> emb; row sumsq -> atomicAdd
  float bb[2];
#pragma unroll
  for (int j = 0; j < 2; ++j) bb[j] = bias[bn0 + wc * 32 + j * 16 + m16];
#pragma unroll
  for (int i = 0; i < 2; ++i)
#pragma unroll
    for (int r = 0; r < 4; ++r) {
      int rowl = wr * 32 + i * 16 + q * 4 + r;
      float ssq = 0.f;
#pragma unroll
      for (int j = 0; j < 2; ++j) {
        float v = fmaxf(acc[i][j][r] + bb[j], 0.f);
        ushort_t o = f2bf(v);
        float fb = bf2f(o);
        ssq += fb * fb;
        emb[(size_t)(bm0 + rowl) * E_ + bn0 + wc * 32 + j * 16 + m16] = o;
      }
      // sum across the 16 lanes (m16) of this q-group: same row, different cols
      ssq += __shfl_xor(ssq, 1);
      ssq += __shfl_xor(ssq, 2);
      ssq += __shfl_xor(ssq, 4);
      ssq += __shfl_xor(ssq, 8);
      if (m16 == 0) atomicAdd(&sumsq_e[bm0 + rowl], ssq);
    }
}

// =====================================================================
// GEMM2: 256x256 tile, BK=64, 8 waves (2Mx4N), 8-phase schedule with
// XOR-swizzled LDS (T2), counted vmcnt (T3+T4), setprio (T5).
// Row normalizer computed inline from sumsq_e (replaces inv_a).
// =====================================================================
__device__ __forceinline__ void stage_A2(const ushort_t* __restrict__ A, ushort_t* Abuf,
                                         int bm0, int tk, int h, int tid) {
#pragma unroll
  for (int j = 0; j < 2; ++j) {
    int off = j * 8192 + tid * 16;          // byte offset within the 16KB half
    int sl = off >> 7;                      // storage row within half (0..127)
    int cb = off & 127;                     // byte col within row (16-aligned)
    int r  = ((sl >> 6) & 1) * 128 + h * 64 + (sl & 63);  // global tile row
    int cg = cb ^ ((sl & 7) << 4);          // pre-swizzled source col byte
    async_load16(A + (size_t)(bm0 + r) * E_ + tk * 64 + (cg >> 1),
                 Abuf + h * 8192 + j * 4096 + (tid >> 6) * 512);
  }
}

__device__ __forceinline__ void stage_B2(const ushort_t* __restrict__ Bt, ushort_t* Bbuf,
                                         int bn0, int tk, int h, int tid) {
#pragma unroll
  for (int j = 0; j < 2; ++j) {
    int off = j * 8192 + tid * 16;
    int sl = off >> 7;
    int cb = off & 127;
    int r  = ((sl >> 5) & 3) * 64 + h * 32 + (sl & 31);   // global tile N-row
    int cg = cb ^ ((sl & 7) << 4);
    async_load16(Bt + (size_t)(bn0 + r) * E_ + tk * 64 + (cg >> 1),
                 Bbuf + h * 8192 + j * 4096 + (tid >> 6) * 512);
  }
}

template <int MH, int NH>
__device__ __forceinline__ void ph_loads(const ushort_t* Ab, const ushort_t* Bb,
                                         int wr, int wc, int m16, int co0, int co1,
                                         short8 (&af)[4][2], short8 (&bfr)[2][2]) {
#pragma unroll
  for (int f = 0; f < 4; ++f) {
    const ushort_t* p = Ab + (MH * 128 + wr * 64 + f * 16 + m16) * 64;
    af[f][0] = *(const short8*)(p + co0);
    af[f][1] = *(const short8*)(p + co1);
  }
#pragma unroll
  for (int g = 0; g < 2; ++g) {
    const ushort_t* p = Bb + (NH * 128 + wc * 32 + g * 16 + m16) * 64;
    bfr[g][0] = *(const short8*)(p + co0);
    bfr[g][1] = *(const short8*)(p + co1);
  }
}

template <int MH, int NH>
__device__ __forceinline__ void ph_mma(const short8 (&af)[4][2], const short8 (&bfr)[2][2],
                                       floatx4 (&acc)[2][2][4][2]) {
  __builtin_amdgcn_s_setprio(1);
#pragma unroll
  for (int kc = 0; kc < 2; ++kc)
#pragma unroll
    for (int f = 0; f < 4; ++f)
#pragma unroll
      for (int g = 0; g < 2; ++g)
        acc[MH][NH][f][g] =
            __builtin_amdgcn_mfma_f32_16x16x32_bf16(af[f][kc], bfr[g][kc], acc[MH][NH][f][g], 0, 0, 0);
  __builtin_amdgcn_s_setprio(0);
}

__device__ __forceinline__ void out2_batch(float* __restrict__ out2, float pew,
                                           int bm0, int bn0, int b, int w, int l) {
#pragma unroll
  for (int rr = 0; rr < 4; ++rr) {
    float v = __uint_as_float(__builtin_amdgcn_readlane(__float_as_uint(pew), b * 4 + rr));
    int row = bm0 + w * 32 + b * 4 + rr;
    floatx4 vv = {v, v, v, v};
    *(floatx4*)(out2 + (size_t)row * N_ + bn0 + (l << 2)) = vv;
  }
}

#define PH(MH, NH, AB, BB, STAGE, WAIT) \
  { short8 af[4][2]; short8 bfr[2][2];                                  \
    ph_loads<MH, NH>(AB, BB, wr, wc, m16, co0, co1, af, bfr);           \
    STAGE; WAIT;                                                        \
    BAR();                                                              \
    ph_mma<MH, NH>(af, bfr, acc);                                       \
    BAR(); }

__global__ __launch_bounds__(512, 2) void gemm2_8ph(const ushort_t* __restrict__ A,
                                                    const ushort_t* __restrict__ Bt,
                                                    const float* __restrict__ sumsq_e,
                                                    const float* __restrict__ inv_b,
                                                    const float* __restrict__ pe,
                                                    float* __restrict__ out) {
  __shared__ __align__(16) ushort_t As_[2][16384];
  __shared__ __align__(16) ushort_t Bs_[2][16384];
  const int tid = threadIdx.x, w = tid >> 6, l = tid & 63;
  const int m16 = l & 15, q = l >> 4;
  const int wr = w >> 2, wc = w & 3;
  const int bm0 = blockIdx.y * 256, bn0 = blockIdx.x * 256;
  const int swz = (m16 & 7) << 4;
  const int co0 = ((q * 16) ^ swz) >> 1;         // kc=0 swizzled col (elems)
  const int co1 = ((64 + q * 16) ^ swz) >> 1;    // kc=1
  float* out2 = out + (size_t)B_ * N_;

  floatx4 acc[2][2][4][2] = {};

  float pew = pe[bm0 + w * 32 + (l & 31)];
  VMW(0);

  stage_A2(A, As_[0], bm0, 0, 0, tid);
  stage_A2(A, As_[0], bm0, 0, 1, tid);
  stage_B2(Bt, Bs_[0], bn0, 0, 0, tid);
  stage_B2(Bt, Bs_[0], bn0, 0, 1, tid);
  stage_A2(A, As_[1], bm0, 1, 0, tid);
  stage_B2(Bt, Bs_[1], bn0, 1, 0, tid);
  VMW(4);            // tile0 landed; tile1 A0,B0 in flight
  BAR();

#pragma unroll
  for (int i = 0; i < 4; ++i) {
    const int t1 = 2 * i + 1, t2 = 2 * i + 2, t3 = 2 * i + 3;
    const bool pre = (i < 3);
    out2_batch(out2, pew, bm0, bn0, 2 * i, w, l);
    PH(0, 0, As_[0], Bs_[0], stage_A2(A, As_[1], bm0, t1, 1, tid), ;)
    PH(0, 1, As_[0], Bs_[0], stage_B2(Bt, Bs_[1], bn0, t1, 1, tid), ;)
    PH(1, 0, As_[0], Bs_[0], if (pre) stage_A2(A, As_[0], bm0, t2, 0, tid), ;)
    PH(1, 1, As_[0], Bs_[0],
       if (pre) stage_B2(Bt, Bs_[0], bn0, t2, 0, tid),
       if (pre) { VMW(4); } else { VMW(0); })
    out2_batch(out2, pew, bm0, bn0, 2 * i + 1, w, l);
    PH(0, 0, As_[1], Bs_[1], if (pre) stage_A2(A, As_[0], bm0, t2, 1, tid), ;)
    PH(0, 1, As_[1], Bs_[1], if (pre) stage_B2(Bt, Bs_[0], bn0, t2, 1, tid), ;)
    PH(1, 0, As_[1], Bs_[1], if (pre) stage_A2(A, As_[1], bm0, t3, 0, tid), ;)
    PH(1, 1, As_[1], Bs_[1],
       if (pre) stage_B2(Bt, Bs_[1], bn0, t3, 0, tid),
       if (pre) { VMW(4); })
  }

  float ibv[2][2];
#pragma unroll
  for (int nh = 0; nh < 2; ++nh)
#pragma unroll
    for (int g = 0; g < 2; ++g)
      ibv[nh][g] = inv_b[bn0 + wc * 64 + nh * 32 + g * 16 + m16];
#pragma unroll
  for (int mh = 0; mh < 2; ++mh)
#pragma unroll
    for (int f = 0; f < 4; ++f)
#pragma unroll
      for (int rr = 0; rr < 4; ++rr) {
        int row = bm0 + wr * 128 + mh * 64 + f * 16 + q * 4 + rr;
        float ia = 1.f / fmaxf(sqrtf(sumsq_e[row]), 1e-8f);
        size_t base = (size_t)row * N_ + bn0 + wc * 64;
#pragma unroll
        for (int nh = 0; nh < 2; ++nh)
#pragma unroll
          for (int g = 0; g < 2; ++g)
            out[base + nh * 32 + g * 16 + m16] = acc[mh][nh][f][g][rr] * ia * ibv[nh][g];
      }
}

extern "C" void kernel_launch(void* const* d_in, const int* in_sizes, int n_in,
                              void* d_out, int out_size, void* d_ws, size_t ws_size,
                              hipStream_t stream) {
  (void)in_sizes; (void)n_in; (void)out_size; (void)ws_size;
  const float* vf    = (const float*)d_in[0];
  const float* p_wfs = (const float*)d_in[1];
  const float* n_wfs = (const float*)d_in[2];
  const float* gamma = (const float*)d_in[3];
  const float* beta  = (const float*)d_in[4];
  const float* W     = (const float*)d_in[5];
  const float* bias  = (const float*)d_in[6];
  float* out = (float*)d_out;

  char* ws = (char*)d_ws;
  float* psum    = (float*)ws;  ws += (size_t)64 * D_ * 4;
  float* psq     = (float*)ws;  ws += (size_t)64 * D_ * 4;
  float* scale   = (float*)ws;  ws += (size_t)D_ * 4;
  float* shift   = (float*)ws;  ws += (size_t)D_ * 4;
  float* pe      = (float*)ws;  ws += (size_t)B_ * 4;
  float* inv_nw  = (float*)ws;  ws += (size_t)N_ * 4;
  float* sumsq_e = (float*)ws;  ws += (size_t)B_ * 4;
  ushort_t* vfn  = (ushort_t*)ws;  ws += (size_t)B_ * D_ * 2;
  ushort_t* wb   = (ushort_t*)ws;  ws += (size_t)E_ * D_ * 2;
  ushort_t* nwb  = (ushort_t*)ws;  ws += (size_t)N_ * E_ * 2;
  ushort_t* emb  = (ushort_t*)ws;  ws += (size_t)B_ * E_ * 2;

  stats_cast<<<4352, 256, 0, stream>>>(vf, W, n_wfs, psum, psq, wb, nwb, inv_nw);
  bn_finalize<<<16, 256, 0, stream>>>(psum, psq, gamma, beta, scale, shift, sumsq_e);
  pe_cast<<<B_ / 4, 256, 0, stream>>>(vf, p_wfs, scale, shift, vfn, pe);
  gemm1_onepass<<<dim3(E_ / 64, B_ / 64), 256, 0, stream>>>(vfn, wb, bias, emb, sumsq_e);
  gemm2_8ph<<<dim3(N_ / 256, B_ / 256), 512, 0, stream>>>(emb, nwb, sumsq_e, inv_nw, pe, out);
}

// Round 6
// 267.790 us; speedup vs baseline: 1.0519x; 1.0519x over previous
//
#include <hip/hip_runtime.h>
#include <stdint.h>
#include <stddef.h>

#define B_ 2048
#define D_ 4096
#define E_ 512
#define N_ 8192
#define SPLITK 4

typedef unsigned short ushort_t;
typedef __attribute__((ext_vector_type(8))) short short8;
typedef __attribute__((ext_vector_type(4))) float floatx4;
typedef __attribute__((ext_vector_type(4))) unsigned short ushort4_t;

__device__ __forceinline__ void async_load16(const void* g, void* l) {
  __builtin_amdgcn_global_load_lds((__attribute__((address_space(1))) void*)(g),
                                   (__attribute__((address_space(3))) void*)(l), 16, 0, 0);
}

__device__ __forceinline__ ushort_t f2bf(float f) {
  unsigned int u = __float_as_uint(f);
  unsigned int r = (u + 0x7fffu + ((u >> 16) & 1u)) >> 16;
  return (ushort_t)r;
}
__device__ __forceinline__ float bf2f(ushort_t h) {
  return __uint_as_float(((unsigned int)h) << 16);
}

#define BAR() asm volatile("s_barrier" ::: "memory")
#define VMW(n) asm volatile("s_waitcnt vmcnt(" #n ")" ::: "memory")
#define LGKM0() asm volatile("s_waitcnt lgkmcnt(0)" ::: "memory")

// ---------------- BatchNorm partial stats (float4) ----------------
__global__ __launch_bounds__(256) void bn_partial(const float* __restrict__ vf,
                                                  float* __restrict__ psum,
                                                  float* __restrict__ psq) {
  int d4 = blockIdx.x * 256 + threadIdx.x;
  int chunk = blockIdx.y;
  floatx4 s = {0.f, 0.f, 0.f, 0.f}, q = {0.f, 0.f, 0.f, 0.f};
  int r0 = chunk * 32;
  for (int r = r0; r < r0 + 32; ++r) {
    floatx4 v = ((const floatx4*)(vf + (size_t)r * D_))[d4];
    s += v; q += v * v;
  }
  ((floatx4*)(psum + (size_t)chunk * D_))[d4] = s;
  ((floatx4*)(psq  + (size_t)chunk * D_))[d4] = q;
}

// ---------------- prep: bn finalize + W cast + n_wfs cast/norms (3-way fused) ----------------
__global__ __launch_bounds__(256) void prep_all(const float* __restrict__ psum,
                                                const float* __restrict__ psq,
                                                const float* __restrict__ gamma,
                                                const float* __restrict__ beta,
                                                const float* __restrict__ W,
                                                const float* __restrict__ nw,
                                                float* __restrict__ scale,
                                                float* __restrict__ shift,
                                                ushort_t* __restrict__ wb,
                                                ushort_t* __restrict__ nwb,
                                                float* __restrict__ inv_nw) {
  int bid = blockIdx.x;
  if (bid < 4) {
    int d4 = bid * 256 + threadIdx.x;   // 0..1023
    floatx4 s = {0.f, 0.f, 0.f, 0.f}, q = {0.f, 0.f, 0.f, 0.f};
    for (int c = 0; c < 64; ++c) {
      s += ((const floatx4*)(psum + (size_t)c * D_))[d4];
      q += ((const floatx4*)(psq  + (size_t)c * D_))[d4];
    }
    floatx4 g = ((const floatx4*)gamma)[d4];
    floatx4 bt = ((const floatx4*)beta)[d4];
    floatx4 sc, sh;
#pragma unroll
    for (int j = 0; j < 4; ++j) {
      float mean = s[j] * (1.0f / B_);
      float var  = q[j] * (1.0f / B_) - mean * mean;
      float scj  = g[j] * rsqrtf(var + 1e-5f);
      sc[j] = scj;
      sh[j] = bt[j] - mean * scj;
    }
    ((floatx4*)scale)[d4] = sc;
    ((floatx4*)shift)[d4] = sh;
  } else if (bid < 2052) {
    size_t i = ((size_t)(bid - 4) * 256 + threadIdx.x) * 4;
    floatx4 x = *(const floatx4*)(W + i);
    ushort4_t o;
#pragma unroll
    for (int j = 0; j < 4; ++j) o[j] = f2bf(x[j]);
    *(ushort4_t*)(wb + i) = o;
  } else {
    int wv = threadIdx.x >> 6, l = threadIdx.x & 63;
    int n = (bid - 2052) * 4 + wv;
    const floatx4* src = (const floatx4*)(nw + (size_t)n * E_);
    ushort4_t* dst = (ushort4_t*)(nwb + (size_t)n * E_);
    float s = 0.f;
#pragma unroll
    for (int k = 0; k < 2; ++k) {
      floatx4 x = src[l + 64 * k];
      ushort4_t o;
#pragma unroll
      for (int j = 0; j < 4; ++j) { o[j] = f2bf(x[j]); s += x[j] * x[j]; }
      dst[l + 64 * k] = o;
    }
    for (int off = 32; off; off >>= 1) s += __shfl_down(s, off);
    if (l == 0) inv_nw[n] = 1.f / fmaxf(sqrtf(s), 1e-8f);
  }
}

// ---------------- fused: p_e cosine + vfn bf16 cast (one wave per row) ----------------
__global__ __launch_bounds__(256) void pe_cast(const float* __restrict__ vf,
                                               const float* __restrict__ p,
                                               const float* __restrict__ scale,
                                               const float* __restrict__ shift,
                                               ushort_t* __restrict__ vfn,
                                               float* __restrict__ pe) {
  int wv = threadIdx.x >> 6, l = threadIdx.x & 63;
  int v = blockIdx.x * 4 + wv;
  const floatx4* vf4 = (const floatx4*)(vf + (size_t)v * D_);
  const floatx4* p4  = (const floatx4*)(p  + (size_t)v * D_);
  const floatx4* sc4 = (const floatx4*)scale;
  const floatx4* sh4 = (const floatx4*)shift;
  ushort_t* vrow = vfn + (size_t)v * D_;
  float sd = 0.f, sa = 0.f, sb = 0.f;
#pragma unroll 4
  for (int k = 0; k < 16; ++k) {
    int i = l + 64 * k;
    floatx4 x = vf4[i], y = p4[i], s = sc4[i], t = sh4[i];
    ushort4_t o;
#pragma unroll
    for (int j = 0; j < 4; ++j) {
      float xn = x[j] * s[j] + t[j];
      o[j] = f2bf(xn);
      sd += xn * y[j]; sa += xn * xn; sb += y[j] * y[j];
    }
    *(ushort4_t*)(vrow + i * 4) = o;
  }
  for (int off = 32; off; off >>= 1) {
    sd += __shfl_down(sd, off); sa += __shfl_down(sa, off); sb += __shfl_down(sb, off);
  }
  if (l == 0) {
    float na = fmaxf(sqrtf(sa), 1e-8f), nb = fmaxf(sqrtf(sb), 1e-8f);
    pe[v] = sd / (na * nb);
  }
}

// =====================================================================
// GEMM1 split-K: 128x64 tile, BK=64, LDS double-buffered, T2 XOR-swizzle
// (linear LDS dest via global_load_lds, pre-swizzled global SOURCE,
// swizzled ds_read), counted vmcnt(6) (never drained mid-loop), raw
// s_barrier + explicit lgkmcnt(0), setprio around the MFMA cluster.
// =====================================================================
__global__ __launch_bounds__(256, 2) void gemm1_splitk(const ushort_t* __restrict__ A,
                                                       const ushort_t* __restrict__ Bt,
                                                       float* __restrict__ partial) {
  __shared__ __align__(16) ushort_t As[2][128 * 64];
  __shared__ __align__(16) ushort_t Bs[2][64 * 64];
  floatx4 acc[4][2] = {};
  const int tid = threadIdx.x, w = tid >> 6, l = tid & 63;
  const int m16 = l & 15, q = l >> 4;
  const int wr = w >> 1, wc = w & 1;
  const int bm0 = blockIdx.y * 128, bn0 = blockIdx.x * 64;
  const int kb = blockIdx.z * (D_ / SPLITK);

  auto stageA = [&](int t, int b) {
#pragma unroll
    for (int i = 0; i < 4; ++i) {
      int lin = i * 2048 + tid * 8;
      int row = lin >> 6, colp = lin & 63;
      int col = colp ^ ((row & 7) << 3);          // pre-swizzled source col
      async_load16(A + (size_t)(bm0 + row) * D_ + kb + t * 64 + col,
                   &As[b][i * 2048 + w * 512]);
    }
  };
  auto stageB = [&](int t, int b) {
#pragma unroll
    for (int i = 0; i < 2; ++i) {
      int lin = i * 2048 + tid * 8;
      int row = lin >> 6, colp = lin & 63;
      int col = colp ^ ((row & 7) << 3);
      async_load16(Bt + (size_t)(bn0 + row) * D_ + kb + t * 64 + col,
                   &Bs[b][i * 2048 + w * 512]);
    }
  };

  // prologue: tiles 0 (buf0) and 1 (buf1); wait tile0 only (6 loads stay in flight)
  stageA(0, 0); stageB(0, 0);
  stageA(1, 1); stageB(1, 1);
  VMW(6);
  BAR();

  for (int t = 0; t < 16; ++t) {
    const int cur = t & 1;
    short8 af[4][2], bf[2][2];
#pragma unroll
    for (int i = 0; i < 4; ++i) {
      int arow = wr * 64 + i * 16 + m16;
      int sw = (arow & 7) << 3;
#pragma unroll
      for (int kc = 0; kc < 2; ++kc)
        af[i][kc] = *(const short8*)&As[cur][arow * 64 + ((kc * 32 + q * 8) ^ sw)];
    }
#pragma unroll
    for (int j = 0; j < 2; ++j) {
      int brow = wc * 32 + j * 16 + m16;
      int sw = (brow & 7) << 3;
#pragma unroll
      for (int kc = 0; kc < 2; ++kc)
        bf[j][kc] = *(const short8*)&Bs[cur][brow * 64 + ((kc * 32 + q * 8) ^ sw)];
    }
    LGKM0();                 // our reads of buf[cur] complete
    BAR();                   // all waves done reading buf[cur] -> safe to overwrite
    if (t + 2 < 16) { stageA(t + 2, cur); stageB(t + 2, cur); }
    __builtin_amdgcn_s_setprio(1);
#pragma unroll
    for (int kc = 0; kc < 2; ++kc)
#pragma unroll
      for (int i = 0; i < 4; ++i)
#pragma unroll
        for (int j = 0; j < 2; ++j)
          acc[i][j] = __builtin_amdgcn_mfma_f32_16x16x32_bf16(af[i][kc], bf[j][kc], acc[i][j], 0, 0, 0);
    __builtin_amdgcn_s_setprio(0);
    if (t + 2 < 16) { VMW(6); } else { VMW(0); }   // buf[cur^1] landed; newest 6 stay in flight
    BAR();
  }

  float* out = partial + (size_t)blockIdx.z * B_ * E_;
#pragma unroll
  for (int i = 0; i < 4; ++i)
#pragma unroll
    for (int j = 0; j < 2; ++j) {
      int col = bn0 + wc * 32 + j * 16 + m16;
#pragma unroll
      for (int r = 0; r < 4; ++r) {
        int row = bm0 + wr * 64 + i * 16 + q * 4 + r;
        out[(size_t)row * E_ + col] = acc[i][j][r];
      }
    }
}

// Reduce splits + bias + ReLU + bf16 cast + row inv-norm. Wave per row, no LDS.
__global__ __launch_bounds__(256) void gemm1_reduce(const float* __restrict__ partial,
                                                    const float* __restrict__ bias,
                                                    ushort_t* __restrict__ emb,
                                                    float* __restrict__ inv_emb) {
  int wv = threadIdx.x >> 6, l = threadIdx.x & 63;
  int row = blockIdx.x * 4 + wv;
  float sumsq = 0.f;
#pragma unroll
  for (int k = 0; k < 2; ++k) {
    int i = l + 64 * k;
    floatx4 v = {0.f, 0.f, 0.f, 0.f};
#pragma unroll
    for (int s = 0; s < SPLITK; ++s)
      v += ((const floatx4*)(partial + (size_t)s * B_ * E_ + (size_t)row * E_))[i];
    floatx4 bb = ((const floatx4*)bias)[i];
    ushort4_t o;
#pragma unroll
    for (int j = 0; j < 4; ++j) {
      float f = fmaxf(v[j] + bb[j], 0.f);
      o[j] = f2bf(f);
      float fb = bf2f(o[j]);
      sumsq += fb * fb;
    }
    ((ushort4_t*)(emb + (size_t)row * E_))[i] = o;
  }
  for (int off = 32; off; off >>= 1) sumsq += __shfl_down(sumsq, off);
  if (l == 0) inv_emb[row] = 1.f / fmaxf(sqrtf(sumsq), 1e-8f);
}

// =====================================================================
// GEMM2: 256x256 tile, BK=64, 8 waves (2Mx4N), 8-phase schedule with
// XOR-swizzled LDS (T2), counted vmcnt (T3+T4), setprio (T5).
// =====================================================================
__device__ __forceinline__ void stage_A2(const ushort_t* __restrict__ A, ushort_t* Abuf,
                                         int bm0, int tk, int h, int tid) {
#pragma unroll
  for (int j = 0; j < 2; ++j) {
    int off = j * 8192 + tid * 16;          // byte offset within the 16KB half
    int sl = off >> 7;                      // storage row within half (0..127)
    int cb = off & 127;                     // byte col within row (16-aligned)
    int r  = ((sl >> 6) & 1) * 128 + h * 64 + (sl & 63);  // global tile row
    int cg = cb ^ ((sl & 7) << 4);          // pre-swizzled source col byte
    async_load16(A + (size_t)(bm0 + r) * E_ + tk * 64 + (cg >> 1),
                 Abuf + h * 8192 + j * 4096 + (tid >> 6) * 512);
  }
}

__device__ __forceinline__ void stage_B2(const ushort_t* __restrict__ Bt, ushort_t* Bbuf,
                                         int bn0, int tk, int h, int tid) {
#pragma unroll
  for (int j = 0; j < 2; ++j) {
    int off = j * 8192 + tid * 16;
    int sl = off >> 7;
    int cb = off & 127;
    int r  = ((sl >> 5) & 3) * 64 + h * 32 + (sl & 31);   // global tile N-row
    int cg = cb ^ ((sl & 7) << 4);
    async_load16(Bt + (size_t)(bn0 + r) * E_ + tk * 64 + (cg >> 1),
                 Bbuf + h * 8192 + j * 4096 + (tid >> 6) * 512);
  }
}

template <int MH, int NH>
__device__ __forceinline__ void ph_loads(const ushort_t* Ab, const ushort_t* Bb,
                                         int wr, int wc, int m16, int co0, int co1,
                                         short8 (&af)[4][2], short8 (&bfr)[2][2]) {
#pragma unroll
  for (int f = 0; f < 4; ++f) {
    const ushort_t* p = Ab + (MH * 128 + wr * 64 + f * 16 + m16) * 64;
    af[f][0] = *(const short8*)(p + co0);
    af[f][1] = *(const short8*)(p + co1);
  }
#pragma unroll
  for (int g = 0; g < 2; ++g) {
    const ushort_t* p = Bb + (NH * 128 + wc * 32 + g * 16 + m16) * 64;
    bfr[g][0] = *(const short8*)(p + co0);
    bfr[g][1] = *(const short8*)(p + co1);
  }
}

template <int MH, int NH>
__device__ __forceinline__ void ph_mma(const short8 (&af)[4][2], const short8 (&bfr)[2][2],
                                       floatx4 (&acc)[2][2][4][2]) {
  __builtin_amdgcn_s_setprio(1);
#pragma unroll
  for (int kc = 0; kc < 2; ++kc)
#pragma unroll
    for (int f = 0; f < 4; ++f)
#pragma unroll
      for (int g = 0; g < 2; ++g)
        acc[MH][NH][f][g] =
            __builtin_amdgcn_mfma_f32_16x16x32_bf16(af[f][kc], bfr[g][kc], acc[MH][NH][f][g], 0, 0, 0);
  __builtin_amdgcn_s_setprio(0);
}

__device__ __forceinline__ void out2_batch(float* __restrict__ out2, float pew,
                                           int bm0, int bn0, int b, int w, int l) {
#pragma unroll
  for (int rr = 0; rr < 4; ++rr) {
    float v = __uint_as_float(__builtin_amdgcn_readlane(__float_as_uint(pew), b * 4 + rr));
    int row = bm0 + w * 32 + b * 4 + rr;
    floatx4 vv = {v, v, v, v};
    *(floatx4*)(out2 + (size_t)row * N_ + bn0 + (l << 2)) = vv;
  }
}

#define PH(MH, NH, AB, BB, STAGE, WAIT) \
  { short8 af[4][2]; short8 bfr[2][2];                                  \
    ph_loads<MH, NH>(AB, BB, wr, wc, m16, co0, co1, af, bfr);           \
    STAGE; WAIT;                                                        \
    BAR();                                                              \
    ph_mma<MH, NH>(af, bfr, acc);                                       \
    BAR(); }

__global__ __launch_bounds__(512, 2) void gemm2_8ph(const ushort_t* __restrict__ A,
                                                    const ushort_t* __restrict__ Bt,
                                                    const float* __restrict__ inv_a,
                                                    const float* __restrict__ inv_b,
                                                    const float* __restrict__ pe,
                                                    float* __restrict__ out) {
  __shared__ __align__(16) ushort_t As_[2][16384];
  __shared__ __align__(16) ushort_t Bs_[2][16384];
  const int tid = threadIdx.x, w = tid >> 6, l = tid & 63;
  const int m16 = l & 15, q = l >> 4;
  const int wr = w >> 2, wc = w & 3;
  const int bm0 = blockIdx.y * 256, bn0 = blockIdx.x * 256;
  const int swz = (m16 & 7) << 4;
  const int co0 = ((q * 16) ^ swz) >> 1;         // kc=0 swizzled col (elems)
  const int co1 = ((64 + q * 16) ^ swz) >> 1;    // kc=1
  float* out2 = out + (size_t)B_ * N_;

  floatx4 acc[2][2][4][2] = {};

  float pew = pe[bm0 + w * 32 + (l & 31)];
  VMW(0);

  stage_A2(A, As_[0], bm0, 0, 0, tid);
  stage_A2(A, As_[0], bm0, 0, 1, tid);
  stage_B2(Bt, Bs_[0], bn0, 0, 0, tid);
  stage_B2(Bt, Bs_[0], bn0, 0, 1, tid);
  stage_A2(A, As_[1], bm0, 1, 0, tid);
  stage_B2(Bt, Bs_[1], bn0, 1, 0, tid);
  VMW(4);            // tile0 landed; tile1 A0,B0 in flight
  BAR();

#pragma unroll
  for (int i = 0; i < 4; ++i) {
    const int t1 = 2 * i + 1, t2 = 2 * i + 2, t3 = 2 * i + 3;
    const bool pre = (i < 3);
    out2_batch(out2, pew, bm0, bn0, 2 * i, w, l);
    PH(0, 0, As_[0], Bs_[0], stage_A2(A, As_[1], bm0, t1, 1, tid), ;)
    PH(0, 1, As_[0], Bs_[0], stage_B2(Bt, Bs_[1], bn0, t1, 1, tid), ;)
    PH(1, 0, As_[0], Bs_[0], if (pre) stage_A2(A, As_[0], bm0, t2, 0, tid), ;)
    PH(1, 1, As_[0], Bs_[0],
       if (pre) stage_B2(Bt, Bs_[0], bn0, t2, 0, tid),
       if (pre) { VMW(4); } else { VMW(0); })
    out2_batch(out2, pew, bm0, bn0, 2 * i + 1, w, l);
    PH(0, 0, As_[1], Bs_[1], if (pre) stage_A2(A, As_[0], bm0, t2, 1, tid), ;)
    PH(0, 1, As_[1], Bs_[1], if (pre) stage_B2(Bt, Bs_[0], bn0, t2, 1, tid), ;)
    PH(1, 0, As_[1], Bs_[1], if (pre) stage_A2(A, As_[1], bm0, t3, 0, tid), ;)
    PH(1, 1, As_[1], Bs_[1],
       if (pre) stage_B2(Bt, Bs_[1], bn0, t3, 0, tid),
       if (pre) { VMW(4); })
  }

  float ibv[2][2];
#pragma unroll
  for (int nh = 0; nh < 2; ++nh)
#pragma unroll
    for (int g = 0; g < 2; ++g)
      ibv[nh][g] = inv_b[bn0 + wc * 64 + nh * 32 + g * 16 + m16];
#pragma unroll
  for (int mh = 0; mh < 2; ++mh)
#pragma unroll
    for (int f = 0; f < 4; ++f)
#pragma unroll
      for (int rr = 0; rr < 4; ++rr) {
        int row = bm0 + wr * 128 + mh * 64 + f * 16 + q * 4 + rr;
        float ia = inv_a[row];
        size_t base = (size_t)row * N_ + bn0 + wc * 64;
#pragma unroll
        for (int nh = 0; nh < 2; ++nh)
#pragma unroll
          for (int g = 0; g < 2; ++g)
            out[base + nh * 32 + g * 16 + m16] = acc[mh][nh][f][g][rr] * ia * ibv[nh][g];
      }
}

extern "C" void kernel_launch(void* const* d_in, const int* in_sizes, int n_in,
                              void* d_out, int out_size, void* d_ws, size_t ws_size,
                              hipStream_t stream) {
  (void)in_sizes; (void)n_in; (void)out_size; (void)ws_size;
  const float* vf    = (const float*)d_in[0];
  const float* p_wfs = (const float*)d_in[1];
  const float* n_wfs = (const float*)d_in[2];
  const float* gamma = (const float*)d_in[3];
  const float* beta  = (const float*)d_in[4];
  const float* W     = (const float*)d_in[5];
  const float* bias  = (const float*)d_in[6];
  float* out = (float*)d_out;

  char* ws = (char*)d_ws;
  float* psum    = (float*)ws;  ws += (size_t)64 * D_ * 4;
  float* psq     = (float*)ws;  ws += (size_t)64 * D_ * 4;
  float* scale   = (float*)ws;  ws += (size_t)D_ * 4;
  float* shift   = (float*)ws;  ws += (size_t)D_ * 4;
  float* pe      = (float*)ws;  ws += (size_t)B_ * 4;
  float* inv_nw  = (float*)ws;  ws += (size_t)N_ * 4;
  float* inv_emb = (float*)ws;  ws += (size_t)B_ * 4;
  float* partial = (float*)ws;  ws += (size_t)SPLITK * B_ * E_ * 4;
  ushort_t* vfn  = (ushort_t*)ws;  ws += (size_t)B_ * D_ * 2;
  ushort_t* wb   = (ushort_t*)ws;  ws += (size_t)E_ * D_ * 2;
  ushort_t* nwb  = (ushort_t*)ws;  ws += (size_t)N_ * E_ * 2;
  ushort_t* emb  = (ushort_t*)ws;  ws += (size_t)B_ * E_ * 2;

  bn_partial<<<dim3(D_ / 1024, 64), 256, 0, stream>>>(vf, psum, psq);
  prep_all<<<4 + 2048 + N_ / 4, 256, 0, stream>>>(psum, psq, gamma, beta, W, n_wfs,
                                                  scale, shift, wb, nwb, inv_nw);
  pe_cast<<<B_ / 4, 256, 0, stream>>>(vf, p_wfs, scale, shift, vfn, pe);
  gemm1_splitk<<<dim3(E_ / 64, B_ / 128, SPLITK), 256, 0, stream>>>(vfn, wb, partial);
  gemm1_reduce<<<B_ / 4, 256, 0, stream>>>(partial, bias, emb, inv_emb);
  gemm2_8ph<<<dim3(N_ / 256, B_ / 256), 512, 0, stream>>>(emb, nwb, inv_emb, inv_nw, pe, out);
}